// Round 4
// baseline (1521.542 us; speedup 1.0000x reference)
//
#include <hip/hip_runtime.h>
#include <math.h>

#define HD 128   // HIDDEN_DIM
#define KD 256   // INPUT_DIM

// ---------------- degree count (int), per relation src & dst ----------------
__global__ void deg_kernel(const int* __restrict__ cps, const int* __restrict__ cpd,
                           const int* __restrict__ pcs, const int* __restrict__ pcd,
                           int* c_cps, int* c_pcs, int* c_cpd, int* c_pcd, int E) {
    int e = blockIdx.x * blockDim.x + threadIdx.x;
    if (e >= E) return;
    atomicAdd(c_cps + cps[e], 1);
    atomicAdd(c_pcs + pcs[e], 1);
    atomicAdd(c_cpd + cpd[e], 1);
    atomicAdd(c_pcd + pcd[e], 1);
}

// ---------------- exclusive scan, 3-phase (1024 elems / block) ----------------
__global__ void scanA(int* data, int* bsums, int n) {
    __shared__ int tmp[256];
    const int t = threadIdx.x;
    const int base = blockIdx.x * 1024 + t * 4;
    int v[4], s = 0;
    #pragma unroll
    for (int i = 0; i < 4; ++i) { v[i] = (base + i < n) ? data[base + i] : 0; s += v[i]; }
    tmp[t] = s;
    __syncthreads();
    for (int off = 1; off < 256; off <<= 1) {
        int x = (t >= off) ? tmp[t - off] : 0;
        __syncthreads();
        tmp[t] += x;
        __syncthreads();
    }
    int ex = tmp[t] - s;   // exclusive prefix within block
    #pragma unroll
    for (int i = 0; i < 4; ++i) { if (base + i < n) data[base + i] = ex; ex += v[i]; }
    if (t == 255) bsums[blockIdx.x] = tmp[255];
}

__global__ void scanB(int* bs, int nb) {   // nb <= 256
    __shared__ int tmp[256];
    const int t = threadIdx.x;
    int v = (t < nb) ? bs[t] : 0;
    tmp[t] = v;
    __syncthreads();
    for (int off = 1; off < 256; off <<= 1) {
        int x = (t >= off) ? tmp[t - off] : 0;
        __syncthreads();
        tmp[t] += x;
        __syncthreads();
    }
    if (t < nb) bs[t] = tmp[t] - v;
}

__global__ void scanC(int* data, const int* __restrict__ bsums, int n) {
    const int t = threadIdx.x;
    const int base = blockIdx.x * 1024 + t * 4;
    const int add = bsums[blockIdx.x];
    #pragma unroll
    for (int i = 0; i < 4; ++i) if (base + i < n) data[base + i] += add;
}

// ---------------- int degree -> f32 deg^-1/2, in place ----------------
__global__ void inv_inplace(int* cnt, int n) {
    int i = blockIdx.x * blockDim.x + threadIdx.x;
    if (i >= n) return;
    int d = cnt[i];
    float f = (d > 0) ? (1.0f / sqrtf((float)d)) : 0.0f;
    ((float*)cnt)[i] = f;
}

// ---------------- counting-sort scatter: build dst-sorted src lists ----------------
__global__ void scatter_kernel(const int* __restrict__ cps, const int* __restrict__ cpd,
                               const int* __restrict__ pcs, const int* __restrict__ pcd,
                               int* off_cp, int* off_pc, int* scp, int* spc, int E) {
    int e = blockIdx.x * blockDim.x + threadIdx.x;
    if (e >= E) return;
    int p1 = atomicAdd(off_cp + cpd[e], 1);
    scp[p1] = cps[e];
    int p2 = atomicAdd(off_pc + pcd[e], 1);
    spc[p2] = pcs[e];
}

// ---------------- fp32 GEMM: out = X[M,256] @ W[256,128] + b ----------------
// 128-row x 128-col tile, 256 threads, 8x8 register blocking.
// X streamed from global (wave-broadcast across the 16 col-threads per row);
// W staged in LDS in 64-K chunks (32 KiB) so W is read once per block.
__device__ __forceinline__ void fma4(float4& a, float s, const float4 w) {
    a.x = fmaf(s, w.x, a.x); a.y = fmaf(s, w.y, a.y);
    a.z = fmaf(s, w.z, a.z); a.w = fmaf(s, w.w, a.w);
}

__launch_bounds__(256, 2)
__global__ void gemm_kernel(const float* __restrict__ X, const float* __restrict__ W,
                            const float* __restrict__ bias, float* __restrict__ out0,
                            float* __restrict__ out1, int M) {
    __shared__ float4 Ws[64 * 32];           // 32 KiB: W chunk [64 k][128 cols]
    const int t = threadIdx.x;
    const int tcol = t & 15;                 // 16 col-groups of 8 cols
    const int trow = t >> 4;                 // 16 row-groups, rows trow + r*16
    const int rbase = blockIdx.x * 128;
    const float4* X4 = (const float4*)X;
    const float4* W4 = (const float4*)W;

    float4 acc[8][2];
    const float4 b0 = ((const float4*)bias)[tcol * 2];
    const float4 b1 = ((const float4*)bias)[tcol * 2 + 1];
    #pragma unroll
    for (int r = 0; r < 8; ++r) { acc[r][0] = b0; acc[r][1] = b1; }

    const bool full = (rbase + 128 <= M);

    for (int kc = 0; kc < 4; ++kc) {
        __syncthreads();
        #pragma unroll
        for (int i = 0; i < 8; ++i) {        // stage W[kc*64 .. +63][0..127]
            int q = t + i * 256;             // 2048 float4
            Ws[q] = W4[(size_t)(kc * 64 + (q >> 5)) * 32 + (q & 31)];
        }
        __syncthreads();

        if (full) {
            #pragma unroll 4
            for (int kk = 0; kk < 16; ++kk) {
                float4 xr[8];
                #pragma unroll
                for (int r = 0; r < 8; ++r)
                    xr[r] = X4[(size_t)(rbase + trow + r * 16) * 64 + kc * 16 + kk];
                #pragma unroll
                for (int i = 0; i < 4; ++i) {
                    const float4 wa = Ws[(kk * 4 + i) * 32 + tcol * 2];
                    const float4 wb = Ws[(kk * 4 + i) * 32 + tcol * 2 + 1];
                    #pragma unroll
                    for (int r = 0; r < 8; ++r) {
                        float s = (i == 0) ? xr[r].x : (i == 1) ? xr[r].y
                                : (i == 2) ? xr[r].z : xr[r].w;
                        fma4(acc[r][0], s, wa);
                        fma4(acc[r][1], s, wb);
                    }
                }
            }
        } else {
            #pragma unroll 4
            for (int kk = 0; kk < 16; ++kk) {
                float4 xr[8];
                #pragma unroll
                for (int r = 0; r < 8; ++r) {
                    int g = rbase + trow + r * 16;
                    xr[r] = (g < M) ? X4[(size_t)g * 64 + kc * 16 + kk]
                                    : make_float4(0.f, 0.f, 0.f, 0.f);
                }
                #pragma unroll
                for (int i = 0; i < 4; ++i) {
                    const float4 wa = Ws[(kk * 4 + i) * 32 + tcol * 2];
                    const float4 wb = Ws[(kk * 4 + i) * 32 + tcol * 2 + 1];
                    #pragma unroll
                    for (int r = 0; r < 8; ++r) {
                        float s = (i == 0) ? xr[r].x : (i == 1) ? xr[r].y
                                : (i == 2) ? xr[r].z : xr[r].w;
                        fma4(acc[r][0], s, wa);
                        fma4(acc[r][1], s, wb);
                    }
                }
            }
        }
    }

    #pragma unroll
    for (int r = 0; r < 8; ++r) {
        int g = rbase + trow + r * 16;
        if (g < M) {
            float4* o0 = (float4*)out0 + (size_t)g * 32 + tcol * 2;
            o0[0] = acc[r][0]; o0[1] = acc[r][1];
            float4* o1 = (float4*)out1 + (size_t)g * 32 + tcol * 2;
            o1[0] = acc[r][0]; o1[1] = acc[r][1];
        }
    }
}

// ---------------- CSR aggregation: one 64-lane wave per dst row ----------------
// Two 32-lane halves process edges j (half 0) and j+1 (half 1) concurrently;
// each half-lane owns 4 of the 128 output floats. Shuffles are UNCONDITIONAL
// (full exec mask — a predicated ds_bpermute reading an exec-masked source
// lane returns undefined data; that was round 3's company-only failure).
// Lanes >= n hold wl = 0, so the out-of-range edge (odd n, half 1's last j)
// contributes exactly 0. j = jj + half <= 63 always since jj is even.
__global__ void agg_csr(const int* __restrict__ off, const int* __restrict__ ssrc,
                        const float* __restrict__ invs, const float* __restrict__ hsrc,
                        float* __restrict__ hdst, int M) {
    int row = blockIdx.x * 4 + (threadIdx.x >> 6);
    if (row >= M) return;
    const int lane = threadIdx.x & 63;
    const int half = lane >> 5;
    const int c4 = lane & 31;
    const int end = off[row];
    const int beg = (row > 0) ? off[row - 1] : 0;
    float4 acc = make_float4(0.f, 0.f, 0.f, 0.f);
    const int deg = end - beg;
    if (deg > 0) {
        const float id = 1.0f / sqrtf((float)deg);
        for (int base = beg; base < end; base += 64) {
            int n = end - base;
            if (n > 64) n = 64;
            int sl = 0; float wl = 0.f;
            if (lane < n) {
                sl = ssrc[base + lane];
                wl = invs[sl];
            }
            for (int jj = 0; jj < n; jj += 2) {
                const int j = jj + half;            // <= 63 always
                const int s = __shfl(sl, j);
                const float wt = __shfl(wl, j) * id; // 0 when j >= n
                const float4 v = *(const float4*)(hsrc + (size_t)s * HD + c4 * 4);
                acc.x = fmaf(v.x, wt, acc.x);
                acc.y = fmaf(v.y, wt, acc.y);
                acc.z = fmaf(v.z, wt, acc.z);
                acc.w = fmaf(v.w, wt, acc.w);
            }
        }
    }
    acc.x += __shfl_xor(acc.x, 32);
    acc.y += __shfl_xor(acc.y, 32);
    acc.z += __shfl_xor(acc.z, 32);
    acc.w += __shfl_xor(acc.w, 32);
    if (half == 0)
        *(float4*)(hdst + (size_t)row * HD + c4 * 4) = acc;
}

// ---------------- final: acc = (h0 + l1 + l2)/3, L2-normalize rows ----------------
__global__ void norm_kernel(float* __restrict__ accOut, const float* __restrict__ b1,
                            const float* __restrict__ b2, int M) {
    int row = blockIdx.x * 4 + (threadIdx.x >> 6);
    if (row >= M) return;
    int lane = threadIdx.x & 63;
    size_t base = (size_t)row * HD + (size_t)lane * 2;
    float2 a  = *(const float2*)(accOut + base);
    float2 x1 = *(const float2*)(b1 + base);
    float2 x2 = *(const float2*)(b2 + base);
    const float s = 1.0f / 3.0f;
    float vx = (a.x + x1.x + x2.x) * s;
    float vy = (a.y + x1.y + x2.y) * s;
    float ss = vx * vx + vy * vy;
    #pragma unroll
    for (int off = 32; off > 0; off >>= 1) ss += __shfl_xor(ss, off);
    float inv = 1.0f / fmaxf(sqrtf(ss), 1e-12f);
    float2 r = make_float2(vx * inv, vy * inv);
    *(float2*)(accOut + base) = r;
}

extern "C" void kernel_launch(void* const* d_in, const int* in_sizes, int n_in,
                              void* d_out, int out_size, void* d_ws, size_t ws_size,
                              hipStream_t stream) {
    const float* x_p = (const float*)d_in[0];
    const float* x_c = (const float*)d_in[1];
    const float* W_p = (const float*)d_in[2];
    const float* b_p = (const float*)d_in[3];
    const float* W_c = (const float*)d_in[4];
    const float* b_c = (const float*)d_in[5];
    const int* pcs = (const int*)d_in[6];
    const int* pcd = (const int*)d_in[7];
    const int* cps = (const int*)d_in[8];
    const int* cpd = (const int*)d_in[9];

    const int Np = in_sizes[0] / KD;
    const int Nc = in_sizes[1] / KD;
    const int E  = in_sizes[6];

    // ---- workspace layout (4B words), identical footprint to round 2 ----
    int* scp = (int*)d_ws;                 // [E]
    int* spc = scp + E;                    // [E]
    int* cnt = spc + E;
    int* c_cps = cnt;                      // -> f32 inv (company src deg, cp) [Nc]
    int* c_pcs = c_cps + Nc;               // -> f32 inv (project src deg, pc) [Np]
    int* c_cpd = c_pcs + Np;               // -> off_cp (scan -> END offsets)  [Np]
    int* c_pcd = c_cpd + Np;               // -> off_pc                        [Nc]
    float* bufP0 = (float*)(c_pcd + Nc);   // [Np*HD]
    float* bufP1 = bufP0 + (size_t)Np * HD;
    float* bufC0 = bufP1 + (size_t)Np * HD;
    float* bufC1 = bufC0 + (size_t)Nc * HD;

    float* outP = (float*)d_out;
    float* outC = outP + (size_t)Np * HD;

    int* bsumA = (int*)d_out;        // scan block sums, overwritten by GEMM later
    int* bsumB = bsumA + 128;

    const int ndegall = 2 * (Np + Nc);
    const int ndegsrc = Nc + Np;
    const int nblkP = (Np + 1023) / 1024;
    const int nblkC = (Nc + 1023) / 1024;

    hipMemsetAsync(cnt, 0, (size_t)ndegall * sizeof(int), stream);

    deg_kernel<<<(E + 255) / 256, 256, 0, stream>>>(cps, cpd, pcs, pcd,
                                                    c_cps, c_pcs, c_cpd, c_pcd, E);
    scanA<<<nblkP, 256, 0, stream>>>(c_cpd, bsumA, Np);
    scanA<<<nblkC, 256, 0, stream>>>(c_pcd, bsumB, Nc);
    scanB<<<1, 256, 0, stream>>>(bsumA, nblkP);
    scanB<<<1, 256, 0, stream>>>(bsumB, nblkC);
    scanC<<<nblkP, 256, 0, stream>>>(c_cpd, bsumA, Np);
    scanC<<<nblkC, 256, 0, stream>>>(c_pcd, bsumB, Nc);

    inv_inplace<<<(ndegsrc + 255) / 256, 256, 0, stream>>>(cnt, ndegsrc);

    scatter_kernel<<<(E + 255) / 256, 256, 0, stream>>>(cps, cpd, pcs, pcd,
                                                        c_cpd, c_pcd, scp, spc, E);

    gemm_kernel<<<(Np + 127) / 128, 256, 0, stream>>>(x_p, W_p, b_p, bufP0, outP, Np);
    gemm_kernel<<<(Nc + 127) / 128, 256, 0, stream>>>(x_c, W_c, b_c, bufC0, outC, Nc);

    const float* i_cps = (const float*)c_cps;
    const float* i_pcs = (const float*)c_pcs;

    agg_csr<<<(Np + 3) / 4, 256, 0, stream>>>(c_cpd, scp, i_cps, bufC0, bufP1, Np);
    agg_csr<<<(Nc + 3) / 4, 256, 0, stream>>>(c_pcd, spc, i_pcs, bufP0, bufC1, Nc);
    agg_csr<<<(Np + 3) / 4, 256, 0, stream>>>(c_cpd, scp, i_cps, bufC1, bufP0, Np);
    agg_csr<<<(Nc + 3) / 4, 256, 0, stream>>>(c_pcd, spc, i_pcs, bufP1, bufC0, Nc);

    norm_kernel<<<(Np + 3) / 4, 256, 0, stream>>>(outP, bufP1, bufP0, Np);
    norm_kernel<<<(Nc + 3) / 4, 256, 0, stream>>>(outC, bufC1, bufC0, Nc);
}

// Round 5
// 875.571 us; speedup vs baseline: 1.7378x; 1.7378x over previous
//
#include <hip/hip_runtime.h>
#include <math.h>

#define HD 128   // HIDDEN_DIM
#define KD 256   // INPUT_DIM

// ---------------- degree count (int), per relation src & dst ----------------
__global__ void deg_kernel(const int* __restrict__ cps, const int* __restrict__ cpd,
                           const int* __restrict__ pcs, const int* __restrict__ pcd,
                           int* c_cps, int* c_pcs, int* c_cpd, int* c_pcd, int E) {
    int e = blockIdx.x * blockDim.x + threadIdx.x;
    if (e >= E) return;
    atomicAdd(c_cps + cps[e], 1);
    atomicAdd(c_pcs + pcs[e], 1);
    atomicAdd(c_cpd + cpd[e], 1);
    atomicAdd(c_pcd + pcd[e], 1);
}

// ---------------- exclusive scan, 3-phase (1024 elems / block) ----------------
__global__ void scanA(int* data, int* bsums, int n) {
    __shared__ int tmp[256];
    const int t = threadIdx.x;
    const int base = blockIdx.x * 1024 + t * 4;
    int v[4], s = 0;
    #pragma unroll
    for (int i = 0; i < 4; ++i) { v[i] = (base + i < n) ? data[base + i] : 0; s += v[i]; }
    tmp[t] = s;
    __syncthreads();
    for (int off = 1; off < 256; off <<= 1) {
        int x = (t >= off) ? tmp[t - off] : 0;
        __syncthreads();
        tmp[t] += x;
        __syncthreads();
    }
    int ex = tmp[t] - s;   // exclusive prefix within block
    #pragma unroll
    for (int i = 0; i < 4; ++i) { if (base + i < n) data[base + i] = ex; ex += v[i]; }
    if (t == 255) bsums[blockIdx.x] = tmp[255];
}

__global__ void scanB(int* bs, int nb) {   // nb <= 256
    __shared__ int tmp[256];
    const int t = threadIdx.x;
    int v = (t < nb) ? bs[t] : 0;
    tmp[t] = v;
    __syncthreads();
    for (int off = 1; off < 256; off <<= 1) {
        int x = (t >= off) ? tmp[t - off] : 0;
        __syncthreads();
        tmp[t] += x;
        __syncthreads();
    }
    if (t < nb) bs[t] = tmp[t] - v;
}

__global__ void scanC(int* data, const int* __restrict__ bsums, int n) {
    const int t = threadIdx.x;
    const int base = blockIdx.x * 1024 + t * 4;
    const int add = bsums[blockIdx.x];
    #pragma unroll
    for (int i = 0; i < 4; ++i) if (base + i < n) data[base + i] += add;
}

// ---------------- int degree -> f32 deg^-1/2, in place ----------------
__global__ void inv_inplace(int* cnt, int n) {
    int i = blockIdx.x * blockDim.x + threadIdx.x;
    if (i >= n) return;
    int d = cnt[i];
    float f = (d > 0) ? (1.0f / sqrtf((float)d)) : 0.0f;
    ((float*)cnt)[i] = f;
}

// ---------------- counting-sort scatter: build dst-sorted src lists ----------------
__global__ void scatter_kernel(const int* __restrict__ cps, const int* __restrict__ cpd,
                               const int* __restrict__ pcs, const int* __restrict__ pcd,
                               int* off_cp, int* off_pc, int* scp, int* spc, int E) {
    int e = blockIdx.x * blockDim.x + threadIdx.x;
    if (e >= E) return;
    int p1 = atomicAdd(off_cp + cpd[e], 1);
    scp[p1] = cps[e];
    int p2 = atomicAdd(off_pc + pcd[e], 1);
    spc[p2] = pcs[e];
}

// ---------------- fp32 GEMM: out = X[M,256] @ W[256,128] + b ----------------
// 128-row x 128-col tile, 256 threads, 8x8 thread tile, K chunked by 32.
// BOTH operands staged in LDS (34.8 KB total):
//  - X tile [128 rows][8 f4 +1 pad]: row pad makes trow 0..3 land on distinct
//    bank groups -> conflict-free b128 broadcast reads.
//  - W chunk [32 k][32 f4]: thread owns cols {4*tcol..+3, 64+4*tcol..+3} so a
//    wave's 16 tcol lanes read CONSECUTIVE float4s (2-way aliasing = free).
__device__ __forceinline__ void fma4(float4& a, float s, const float4 w) {
    a.x = fmaf(s, w.x, a.x); a.y = fmaf(s, w.y, a.y);
    a.z = fmaf(s, w.z, a.z); a.w = fmaf(s, w.w, a.w);
}

__launch_bounds__(256, 3)
__global__ void gemm_kernel(const float* __restrict__ X, const float* __restrict__ W,
                            const float* __restrict__ bias, float* __restrict__ out0,
                            float* __restrict__ out1, int M) {
    __shared__ float4 xs[128 * 9];   // 18 KiB (row stride 9 f4: +1 pad)
    __shared__ float4 ws[32 * 32];   // 16 KiB
    const int t = threadIdx.x;
    const int tcol = t & 15;         // col groups: 4*tcol and 64+4*tcol
    const int trow = t >> 4;         // rows trow + r*16
    const int rbase = blockIdx.x * 128;
    const float4* X4 = (const float4*)X;
    const float4* W4 = (const float4*)W;

    float4 acc[8][2];
    const float4 b0 = ((const float4*)bias)[tcol];
    const float4 b1 = ((const float4*)bias)[16 + tcol];
    #pragma unroll
    for (int r = 0; r < 8; ++r) { acc[r][0] = b0; acc[r][1] = b1; }

    for (int kc = 0; kc < 8; ++kc) {           // 8 chunks of BK=32
        __syncthreads();
        #pragma unroll
        for (int i = 0; i < 4; ++i) {          // stage X: 1024 f4
            int q = t + i * 256;
            int row = q >> 3, c = q & 7;
            int g = rbase + row;
            xs[row * 9 + c] = (g < M) ? X4[(size_t)g * 64 + kc * 8 + c]
                                      : make_float4(0.f, 0.f, 0.f, 0.f);
        }
        #pragma unroll
        for (int i = 0; i < 4; ++i) {          // stage W: 1024 f4
            int q = t + i * 256;
            int krow = q >> 5, c = q & 31;
            ws[q] = W4[(size_t)(kc * 32 + krow) * 32 + c];
        }
        __syncthreads();

        #pragma unroll 2
        for (int kk = 0; kk < 8; ++kk) {       // k4 steps within chunk
            float4 xr[8];
            #pragma unroll
            for (int r = 0; r < 8; ++r) xr[r] = xs[(trow + r * 16) * 9 + kk];
            #pragma unroll
            for (int i = 0; i < 4; ++i) {
                const float4 wa = ws[(kk * 4 + i) * 32 + tcol];
                const float4 wb = ws[(kk * 4 + i) * 32 + 16 + tcol];
                #pragma unroll
                for (int r = 0; r < 8; ++r) {
                    float s = (i == 0) ? xr[r].x : (i == 1) ? xr[r].y
                            : (i == 2) ? xr[r].z : xr[r].w;
                    fma4(acc[r][0], s, wa);
                    fma4(acc[r][1], s, wb);
                }
            }
        }
    }

    #pragma unroll
    for (int r = 0; r < 8; ++r) {
        int g = rbase + trow + r * 16;
        if (g < M) {
            ((float4*)out0)[(size_t)g * 32 + tcol]      = acc[r][0];
            ((float4*)out0)[(size_t)g * 32 + 16 + tcol] = acc[r][1];
            ((float4*)out1)[(size_t)g * 32 + tcol]      = acc[r][0];
            ((float4*)out1)[(size_t)g * 32 + 16 + tcol] = acc[r][1];
        }
    }
}

// ---------------- CSR aggregation: one 64-lane wave per dst row ----------------
// Four 16-lane quarters process edges jj..jj+3 concurrently; each quarter-lane
// owns 8 of the 128 output floats (2 independent float4 gathers -> 4x MLP,
// 0.5 VMEM instr per edge). Shuffles UNCONDITIONAL under full exec (round-3
// lesson: predicated ds_bpermute from an exec-masked source lane is undefined).
// Lanes >= n hold wl = 0 so out-of-range slots contribute exactly 0;
// j = jj + q <= 63 always since jj % 4 == 0.
__global__ void agg_csr(const int* __restrict__ off, const int* __restrict__ ssrc,
                        const float* __restrict__ invs, const float* __restrict__ hsrc,
                        float* __restrict__ hdst, int M) {
    int row = blockIdx.x * 4 + (threadIdx.x >> 6);
    if (row >= M) return;
    const int lane = threadIdx.x & 63;
    const int q  = lane >> 4;    // edge slot 0..3
    const int cl = lane & 15;    // column group: floats cl*8 .. +7
    const int end = off[row];
    const int beg = (row > 0) ? off[row - 1] : 0;
    float4 accA = make_float4(0.f, 0.f, 0.f, 0.f);
    float4 accB = make_float4(0.f, 0.f, 0.f, 0.f);
    const int deg = end - beg;
    if (deg > 0) {
        const float id = 1.0f / sqrtf((float)deg);
        for (int base = beg; base < end; base += 64) {
            int n = end - base;
            if (n > 64) n = 64;
            int sl = 0; float wl = 0.f;
            if (lane < n) {
                sl = ssrc[base + lane];
                wl = invs[sl];
            }
            for (int jj = 0; jj < n; jj += 4) {
                const int j = jj + q;                 // <= 63 always
                const int s = __shfl(sl, j);
                const float wt = __shfl(wl, j) * id;  // 0 when j >= n
                const float4* vp = (const float4*)(hsrc + (size_t)s * HD + cl * 8);
                const float4 v0 = vp[0];
                const float4 v1 = vp[1];
                accA.x = fmaf(v0.x, wt, accA.x);
                accA.y = fmaf(v0.y, wt, accA.y);
                accA.z = fmaf(v0.z, wt, accA.z);
                accA.w = fmaf(v0.w, wt, accA.w);
                accB.x = fmaf(v1.x, wt, accB.x);
                accB.y = fmaf(v1.y, wt, accB.y);
                accB.z = fmaf(v1.z, wt, accB.z);
                accB.w = fmaf(v1.w, wt, accB.w);
            }
        }
    }
    // combine the 4 quarters: lanes {cl, cl+16, cl+32, cl+48} share columns
    accA.x += __shfl_xor(accA.x, 16); accA.y += __shfl_xor(accA.y, 16);
    accA.z += __shfl_xor(accA.z, 16); accA.w += __shfl_xor(accA.w, 16);
    accB.x += __shfl_xor(accB.x, 16); accB.y += __shfl_xor(accB.y, 16);
    accB.z += __shfl_xor(accB.z, 16); accB.w += __shfl_xor(accB.w, 16);
    accA.x += __shfl_xor(accA.x, 32); accA.y += __shfl_xor(accA.y, 32);
    accA.z += __shfl_xor(accA.z, 32); accA.w += __shfl_xor(accA.w, 32);
    accB.x += __shfl_xor(accB.x, 32); accB.y += __shfl_xor(accB.y, 32);
    accB.z += __shfl_xor(accB.z, 32); accB.w += __shfl_xor(accB.w, 32);
    if (q < 2) {
        float4 v = (q == 0) ? accA : accB;
        *(float4*)(hdst + (size_t)row * HD + cl * 8 + q * 4) = v;
    }
}

// ---------------- final: acc = (h0 + l1 + l2)/3, L2-normalize rows ----------------
__global__ void norm_kernel(float* __restrict__ accOut, const float* __restrict__ b1,
                            const float* __restrict__ b2, int M) {
    int row = blockIdx.x * 4 + (threadIdx.x >> 6);
    if (row >= M) return;
    int lane = threadIdx.x & 63;
    size_t base = (size_t)row * HD + (size_t)lane * 2;
    float2 a  = *(const float2*)(accOut + base);
    float2 x1 = *(const float2*)(b1 + base);
    float2 x2 = *(const float2*)(b2 + base);
    const float s = 1.0f / 3.0f;
    float vx = (a.x + x1.x + x2.x) * s;
    float vy = (a.y + x1.y + x2.y) * s;
    float ss = vx * vx + vy * vy;
    #pragma unroll
    for (int off = 32; off > 0; off >>= 1) ss += __shfl_xor(ss, off);
    float inv = 1.0f / fmaxf(sqrtf(ss), 1e-12f);
    float2 r = make_float2(vx * inv, vy * inv);
    *(float2*)(accOut + base) = r;
}

extern "C" void kernel_launch(void* const* d_in, const int* in_sizes, int n_in,
                              void* d_out, int out_size, void* d_ws, size_t ws_size,
                              hipStream_t stream) {
    const float* x_p = (const float*)d_in[0];
    const float* x_c = (const float*)d_in[1];
    const float* W_p = (const float*)d_in[2];
    const float* b_p = (const float*)d_in[3];
    const float* W_c = (const float*)d_in[4];
    const float* b_c = (const float*)d_in[5];
    const int* pcs = (const int*)d_in[6];
    const int* pcd = (const int*)d_in[7];
    const int* cps = (const int*)d_in[8];
    const int* cpd = (const int*)d_in[9];

    const int Np = in_sizes[0] / KD;
    const int Nc = in_sizes[1] / KD;
    const int E  = in_sizes[6];

    // ---- workspace layout (4B words), identical footprint to round 2 ----
    int* scp = (int*)d_ws;                 // [E]
    int* spc = scp + E;                    // [E]
    int* cnt = spc + E;
    int* c_cps = cnt;                      // -> f32 inv (company src deg, cp) [Nc]
    int* c_pcs = c_cps + Nc;               // -> f32 inv (project src deg, pc) [Np]
    int* c_cpd = c_pcs + Np;               // -> off_cp (scan -> END offsets)  [Np]
    int* c_pcd = c_cpd + Np;               // -> off_pc                        [Nc]
    float* bufP0 = (float*)(c_pcd + Nc);   // [Np*HD]
    float* bufP1 = bufP0 + (size_t)Np * HD;
    float* bufC0 = bufP1 + (size_t)Np * HD;
    float* bufC1 = bufC0 + (size_t)Nc * HD;

    float* outP = (float*)d_out;
    float* outC = outP + (size_t)Np * HD;

    int* bsumA = (int*)d_out;        // scan block sums, overwritten by GEMM later
    int* bsumB = bsumA + 128;

    const int ndegall = 2 * (Np + Nc);
    const int ndegsrc = Nc + Np;
    const int nblkP = (Np + 1023) / 1024;
    const int nblkC = (Nc + 1023) / 1024;

    hipMemsetAsync(cnt, 0, (size_t)ndegall * sizeof(int), stream);

    deg_kernel<<<(E + 255) / 256, 256, 0, stream>>>(cps, cpd, pcs, pcd,
                                                    c_cps, c_pcs, c_cpd, c_pcd, E);
    scanA<<<nblkP, 256, 0, stream>>>(c_cpd, bsumA, Np);
    scanA<<<nblkC, 256, 0, stream>>>(c_pcd, bsumB, Nc);
    scanB<<<1, 256, 0, stream>>>(bsumA, nblkP);
    scanB<<<1, 256, 0, stream>>>(bsumB, nblkC);
    scanC<<<nblkP, 256, 0, stream>>>(c_cpd, bsumA, Np);
    scanC<<<nblkC, 256, 0, stream>>>(c_pcd, bsumB, Nc);

    inv_inplace<<<(ndegsrc + 255) / 256, 256, 0, stream>>>(cnt, ndegsrc);

    scatter_kernel<<<(E + 255) / 256, 256, 0, stream>>>(cps, cpd, pcs, pcd,
                                                        c_cpd, c_pcd, scp, spc, E);

    gemm_kernel<<<(Np + 127) / 128, 256, 0, stream>>>(x_p, W_p, b_p, bufP0, outP, Np);
    gemm_kernel<<<(Nc + 127) / 128, 256, 0, stream>>>(x_c, W_c, b_c, bufC0, outC, Nc);

    const float* i_cps = (const float*)c_cps;
    const float* i_pcs = (const float*)c_pcs;

    agg_csr<<<(Np + 3) / 4, 256, 0, stream>>>(c_cpd, scp, i_cps, bufC0, bufP1, Np);
    agg_csr<<<(Nc + 3) / 4, 256, 0, stream>>>(c_pcd, spc, i_pcs, bufP0, bufC1, Nc);
    agg_csr<<<(Np + 3) / 4, 256, 0, stream>>>(c_cpd, scp, i_cps, bufC1, bufP0, Np);
    agg_csr<<<(Nc + 3) / 4, 256, 0, stream>>>(c_pcd, spc, i_pcs, bufP1, bufC0, Nc);

    norm_kernel<<<(Np + 3) / 4, 256, 0, stream>>>(outP, bufP1, bufP0, Np);
    norm_kernel<<<(Nc + 3) / 4, 256, 0, stream>>>(outC, bufC1, bufC0, Nc);
}

// Round 6
// 726.360 us; speedup vs baseline: 2.0947x; 1.2054x over previous
//
#include <hip/hip_runtime.h>
#include <hip/hip_bf16.h>
#include <math.h>

#define HD 128   // HIDDEN_DIM
#define KD 256   // INPUT_DIM

// ---- bf16 pack/unpack helpers (storage type: ushort) ----
__device__ __forceinline__ unsigned int pack_bf2(float a, float b) {
    __hip_bfloat162 h;
    h.x = __float2bfloat16(a);
    h.y = __float2bfloat16(b);
    return *(unsigned int*)&h;
}
__device__ __forceinline__ float2 unpack_bf2(unsigned int u) {
    __hip_bfloat162 h = *(__hip_bfloat162*)&u;
    return __bfloat1622float2(h);
}

// ---------------- degree count (int), per relation src & dst ----------------
__global__ void deg_kernel(const int* __restrict__ cps, const int* __restrict__ cpd,
                           const int* __restrict__ pcs, const int* __restrict__ pcd,
                           int* c_cps, int* c_pcs, int* c_cpd, int* c_pcd, int E) {
    int e = blockIdx.x * blockDim.x + threadIdx.x;
    if (e >= E) return;
    atomicAdd(c_cps + cps[e], 1);
    atomicAdd(c_pcs + pcs[e], 1);
    atomicAdd(c_cpd + cpd[e], 1);
    atomicAdd(c_pcd + pcd[e], 1);
}

// ---------------- exclusive scan, 3-phase (1024 elems / block) ----------------
__global__ void scanA(int* data, int* bsums, int n) {
    __shared__ int tmp[256];
    const int t = threadIdx.x;
    const int base = blockIdx.x * 1024 + t * 4;
    int v[4], s = 0;
    #pragma unroll
    for (int i = 0; i < 4; ++i) { v[i] = (base + i < n) ? data[base + i] : 0; s += v[i]; }
    tmp[t] = s;
    __syncthreads();
    for (int off = 1; off < 256; off <<= 1) {
        int x = (t >= off) ? tmp[t - off] : 0;
        __syncthreads();
        tmp[t] += x;
        __syncthreads();
    }
    int ex = tmp[t] - s;   // exclusive prefix within block
    #pragma unroll
    for (int i = 0; i < 4; ++i) { if (base + i < n) data[base + i] = ex; ex += v[i]; }
    if (t == 255) bsums[blockIdx.x] = tmp[255];
}

__global__ void scanB(int* bs, int nb) {   // nb <= 256
    __shared__ int tmp[256];
    const int t = threadIdx.x;
    int v = (t < nb) ? bs[t] : 0;
    tmp[t] = v;
    __syncthreads();
    for (int off = 1; off < 256; off <<= 1) {
        int x = (t >= off) ? tmp[t - off] : 0;
        __syncthreads();
        tmp[t] += x;
        __syncthreads();
    }
    if (t < nb) bs[t] = tmp[t] - v;
}

__global__ void scanC(int* data, const int* __restrict__ bsums, int n) {
    const int t = threadIdx.x;
    const int base = blockIdx.x * 1024 + t * 4;
    const int add = bsums[blockIdx.x];
    #pragma unroll
    for (int i = 0; i < 4; ++i) if (base + i < n) data[base + i] += add;
}

// ---------------- int degree -> f32 deg^-1/2, in place ----------------
__global__ void inv_inplace(int* cnt, int n) {
    int i = blockIdx.x * blockDim.x + threadIdx.x;
    if (i >= n) return;
    int d = cnt[i];
    float f = (d > 0) ? (1.0f / sqrtf((float)d)) : 0.0f;
    ((float*)cnt)[i] = f;
}

// ---------------- counting-sort scatter: build dst-sorted src lists ----------------
__global__ void scatter_kernel(const int* __restrict__ cps, const int* __restrict__ cpd,
                               const int* __restrict__ pcs, const int* __restrict__ pcd,
                               int* off_cp, int* off_pc, int* scp, int* spc, int E) {
    int e = blockIdx.x * blockDim.x + threadIdx.x;
    if (e >= E) return;
    int p1 = atomicAdd(off_cp + cpd[e], 1);
    scp[p1] = cps[e];
    int p2 = atomicAdd(off_pc + pcd[e], 1);
    spc[p2] = pcs[e];
}

// ---------------- fp32 GEMM: out = X[M,256] @ W[256,128] + b ----------------
// 128x128 tile, 256 threads, 8x8 thread tile, K chunked by 32, both operands
// in LDS (conflict-free: X row pad +1 f4; W consecutive-f4 per 16 lanes).
// Epilogue writes bf16 h-buffer (out0) AND fp32 acc seed (out1 = d_out).
__device__ __forceinline__ void fma4(float4& a, float s, const float4 w) {
    a.x = fmaf(s, w.x, a.x); a.y = fmaf(s, w.y, a.y);
    a.z = fmaf(s, w.z, a.z); a.w = fmaf(s, w.w, a.w);
}

__launch_bounds__(256, 3)
__global__ void gemm_kernel(const float* __restrict__ X, const float* __restrict__ W,
                            const float* __restrict__ bias, unsigned short* __restrict__ out0,
                            float* __restrict__ out1, int M) {
    __shared__ float4 xs[128 * 9];   // 18 KiB (row stride 9 f4: +1 pad)
    __shared__ float4 ws[32 * 32];   // 16 KiB
    const int t = threadIdx.x;
    const int tcol = t & 15;         // col groups: 4*tcol and 64+4*tcol
    const int trow = t >> 4;         // rows trow + r*16
    const int rbase = blockIdx.x * 128;
    const float4* X4 = (const float4*)X;
    const float4* W4 = (const float4*)W;

    float4 acc[8][2];
    const float4 b0 = ((const float4*)bias)[tcol];
    const float4 b1 = ((const float4*)bias)[16 + tcol];
    #pragma unroll
    for (int r = 0; r < 8; ++r) { acc[r][0] = b0; acc[r][1] = b1; }

    for (int kc = 0; kc < 8; ++kc) {           // 8 chunks of BK=32
        __syncthreads();
        #pragma unroll
        for (int i = 0; i < 4; ++i) {          // stage X: 1024 f4
            int q = t + i * 256;
            int row = q >> 3, c = q & 7;
            int g = rbase + row;
            xs[row * 9 + c] = (g < M) ? X4[(size_t)g * 64 + kc * 8 + c]
                                      : make_float4(0.f, 0.f, 0.f, 0.f);
        }
        #pragma unroll
        for (int i = 0; i < 4; ++i) {          // stage W: 1024 f4
            int q = t + i * 256;
            int krow = q >> 5, c = q & 31;
            ws[q] = W4[(size_t)(kc * 32 + krow) * 32 + c];
        }
        __syncthreads();

        #pragma unroll 2
        for (int kk = 0; kk < 8; ++kk) {       // k4 steps within chunk
            float4 xr[8];
            #pragma unroll
            for (int r = 0; r < 8; ++r) xr[r] = xs[(trow + r * 16) * 9 + kk];
            #pragma unroll
            for (int i = 0; i < 4; ++i) {
                const float4 wa = ws[(kk * 4 + i) * 32 + tcol];
                const float4 wb = ws[(kk * 4 + i) * 32 + 16 + tcol];
                #pragma unroll
                for (int r = 0; r < 8; ++r) {
                    float s = (i == 0) ? xr[r].x : (i == 1) ? xr[r].y
                            : (i == 2) ? xr[r].z : xr[r].w;
                    fma4(acc[r][0], s, wa);
                    fma4(acc[r][1], s, wb);
                }
            }
        }
    }

    #pragma unroll
    for (int r = 0; r < 8; ++r) {
        int g = rbase + trow + r * 16;
        if (g < M) {
            // fp32 acc seed
            ((float4*)out1)[(size_t)g * 32 + tcol]      = acc[r][0];
            ((float4*)out1)[(size_t)g * 32 + 16 + tcol] = acc[r][1];
            // bf16 h-buffer
            uint2 ua, ub;
            ua.x = pack_bf2(acc[r][0].x, acc[r][0].y);
            ua.y = pack_bf2(acc[r][0].z, acc[r][0].w);
            ub.x = pack_bf2(acc[r][1].x, acc[r][1].y);
            ub.y = pack_bf2(acc[r][1].z, acc[r][1].w);
            uint2* o = (uint2*)(out0 + (size_t)g * HD);
            o[tcol]      = ua;
            o[16 + tcol] = ub;
        }
    }
}

// ---------------- CSR aggregation: one 64-lane wave per dst row ----------------
// bf16 h-rows: 256 B/row, gathered by 16 lanes x 16 B (ONE dwordx4 per lane
// per edge slot). Four 16-lane quarters process edges jj..jj+3 concurrently.
// Shuffles UNCONDITIONAL under full exec (round-3 lesson); lanes >= n hold
// wl = 0 so out-of-range slots contribute exactly 0. Accumulation fp32;
// output row written bf16 by quarter 0 (contiguous 256 B).
__global__ void agg_csr(const int* __restrict__ off, const int* __restrict__ ssrc,
                        const float* __restrict__ invs,
                        const unsigned short* __restrict__ hsrc,
                        unsigned short* __restrict__ hdst, int M) {
    int row = blockIdx.x * 4 + (threadIdx.x >> 6);
    if (row >= M) return;
    const int lane = threadIdx.x & 63;
    const int q  = lane >> 4;    // edge slot 0..3
    const int cl = lane & 15;    // column group: floats cl*8 .. +7
    const int end = off[row];
    const int beg = (row > 0) ? off[row - 1] : 0;
    float4 accA = make_float4(0.f, 0.f, 0.f, 0.f);
    float4 accB = make_float4(0.f, 0.f, 0.f, 0.f);
    const int deg = end - beg;
    if (deg > 0) {
        const float id = 1.0f / sqrtf((float)deg);
        for (int base = beg; base < end; base += 64) {
            int n = end - base;
            if (n > 64) n = 64;
            int sl = 0; float wl = 0.f;
            if (lane < n) {
                sl = ssrc[base + lane];
                wl = invs[sl];
            }
            for (int jj = 0; jj < n; jj += 4) {
                const int j = jj + q;                 // <= 63 always
                const int s = __shfl(sl, j);
                const float wt = __shfl(wl, j) * id;  // 0 when j >= n
                const uint4 u = *(const uint4*)(hsrc + (size_t)s * HD + cl * 8);
                const float2 f0 = unpack_bf2(u.x);
                const float2 f1 = unpack_bf2(u.y);
                const float2 f2 = unpack_bf2(u.z);
                const float2 f3 = unpack_bf2(u.w);
                accA.x = fmaf(f0.x, wt, accA.x);
                accA.y = fmaf(f0.y, wt, accA.y);
                accA.z = fmaf(f1.x, wt, accA.z);
                accA.w = fmaf(f1.y, wt, accA.w);
                accB.x = fmaf(f2.x, wt, accB.x);
                accB.y = fmaf(f2.y, wt, accB.y);
                accB.z = fmaf(f3.x, wt, accB.z);
                accB.w = fmaf(f3.y, wt, accB.w);
            }
        }
    }
    // combine the 4 quarters: lanes {cl, cl+16, cl+32, cl+48} share columns
    accA.x += __shfl_xor(accA.x, 16); accA.y += __shfl_xor(accA.y, 16);
    accA.z += __shfl_xor(accA.z, 16); accA.w += __shfl_xor(accA.w, 16);
    accB.x += __shfl_xor(accB.x, 16); accB.y += __shfl_xor(accB.y, 16);
    accB.z += __shfl_xor(accB.z, 16); accB.w += __shfl_xor(accB.w, 16);
    accA.x += __shfl_xor(accA.x, 32); accA.y += __shfl_xor(accA.y, 32);
    accA.z += __shfl_xor(accA.z, 32); accA.w += __shfl_xor(accA.w, 32);
    accB.x += __shfl_xor(accB.x, 32); accB.y += __shfl_xor(accB.y, 32);
    accB.z += __shfl_xor(accB.z, 32); accB.w += __shfl_xor(accB.w, 32);
    if (q == 0) {
        uint4 u;
        u.x = pack_bf2(accA.x, accA.y);
        u.y = pack_bf2(accA.z, accA.w);
        u.z = pack_bf2(accB.x, accB.y);
        u.w = pack_bf2(accB.z, accB.w);
        *(uint4*)(hdst + (size_t)row * HD + cl * 8) = u;
    }
}

// ---------------- final: acc = (h0 + l1 + l2)/3, L2-normalize rows ----------------
// accOut f32 (d_out, holds h0); b1,b2 bf16 layer outputs.
__global__ void norm_kernel(float* __restrict__ accOut,
                            const unsigned short* __restrict__ b1,
                            const unsigned short* __restrict__ b2, int M) {
    int row = blockIdx.x * 4 + (threadIdx.x >> 6);
    if (row >= M) return;
    int lane = threadIdx.x & 63;
    size_t base = (size_t)row * HD + (size_t)lane * 2;
    float2 a  = *(const float2*)(accOut + base);
    float2 x1 = unpack_bf2(*(const unsigned int*)(b1 + base));
    float2 x2 = unpack_bf2(*(const unsigned int*)(b2 + base));
    const float s = 1.0f / 3.0f;
    float vx = (a.x + x1.x + x2.x) * s;
    float vy = (a.y + x1.y + x2.y) * s;
    float ss = vx * vx + vy * vy;
    #pragma unroll
    for (int off = 32; off > 0; off >>= 1) ss += __shfl_xor(ss, off);
    float inv = 1.0f / fmaxf(sqrtf(ss), 1e-12f);
    float2 r = make_float2(vx * inv, vy * inv);
    *(float2*)(accOut + base) = r;
}

extern "C" void kernel_launch(void* const* d_in, const int* in_sizes, int n_in,
                              void* d_out, int out_size, void* d_ws, size_t ws_size,
                              hipStream_t stream) {
    const float* x_p = (const float*)d_in[0];
    const float* x_c = (const float*)d_in[1];
    const float* W_p = (const float*)d_in[2];
    const float* b_p = (const float*)d_in[3];
    const float* W_c = (const float*)d_in[4];
    const float* b_c = (const float*)d_in[5];
    const int* pcs = (const int*)d_in[6];
    const int* pcd = (const int*)d_in[7];
    const int* cps = (const int*)d_in[8];
    const int* cpd = (const int*)d_in[9];

    const int Np = in_sizes[0] / KD;
    const int Nc = in_sizes[1] / KD;
    const int E  = in_sizes[6];

    // ---- workspace layout: ints then bf16 h-buffers (total ~85 MB) ----
    int* scp = (int*)d_ws;                 // [E]
    int* spc = scp + E;                    // [E]
    int* cnt = spc + E;
    int* c_cps = cnt;                      // -> f32 inv (company src deg, cp) [Nc]
    int* c_pcs = c_cps + Nc;               // -> f32 inv (project src deg, pc) [Np]
    int* c_cpd = c_pcs + Np;               // -> off_cp (scan -> END offsets)  [Np]
    int* c_pcd = c_cpd + Np;               // -> off_pc                        [Nc]
    unsigned short* bufP0 = (unsigned short*)(c_pcd + Nc);   // [Np*HD] bf16
    unsigned short* bufP1 = bufP0 + (size_t)Np * HD;
    unsigned short* bufC0 = bufP1 + (size_t)Np * HD;
    unsigned short* bufC1 = bufC0 + (size_t)Nc * HD;

    float* outP = (float*)d_out;
    float* outC = outP + (size_t)Np * HD;

    int* bsumA = (int*)d_out;        // scan block sums, overwritten by GEMM later
    int* bsumB = bsumA + 128;

    const int ndegall = 2 * (Np + Nc);
    const int ndegsrc = Nc + Np;
    const int nblkP = (Np + 1023) / 1024;
    const int nblkC = (Nc + 1023) / 1024;

    hipMemsetAsync(cnt, 0, (size_t)ndegall * sizeof(int), stream);

    deg_kernel<<<(E + 255) / 256, 256, 0, stream>>>(cps, cpd, pcs, pcd,
                                                    c_cps, c_pcs, c_cpd, c_pcd, E);
    scanA<<<nblkP, 256, 0, stream>>>(c_cpd, bsumA, Np);
    scanA<<<nblkC, 256, 0, stream>>>(c_pcd, bsumB, Nc);
    scanB<<<1, 256, 0, stream>>>(bsumA, nblkP);
    scanB<<<1, 256, 0, stream>>>(bsumB, nblkC);
    scanC<<<nblkP, 256, 0, stream>>>(c_cpd, bsumA, Np);
    scanC<<<nblkC, 256, 0, stream>>>(c_pcd, bsumB, Nc);

    inv_inplace<<<(ndegsrc + 255) / 256, 256, 0, stream>>>(cnt, ndegsrc);

    scatter_kernel<<<(E + 255) / 256, 256, 0, stream>>>(cps, cpd, pcs, pcd,
                                                        c_cpd, c_pcd, scp, spc, E);

    gemm_kernel<<<(Np + 127) / 128, 256, 0, stream>>>(x_p, W_p, b_p, bufP0, outP, Np);
    gemm_kernel<<<(Nc + 127) / 128, 256, 0, stream>>>(x_c, W_c, b_c, bufC0, outC, Nc);

    const float* i_cps = (const float*)c_cps;
    const float* i_pcs = (const float*)c_pcs;

    // layer 1
    agg_csr<<<(Np + 3) / 4, 256, 0, stream>>>(c_cpd, scp, i_cps, bufC0, bufP1, Np);
    agg_csr<<<(Nc + 3) / 4, 256, 0, stream>>>(c_pcd, spc, i_pcs, bufP0, bufC1, Nc);
    // layer 2 (overwrites consumed layer-0 buffers; agg writes every row)
    agg_csr<<<(Np + 3) / 4, 256, 0, stream>>>(c_cpd, scp, i_cps, bufC1, bufP0, Np);
    agg_csr<<<(Nc + 3) / 4, 256, 0, stream>>>(c_pcd, spc, i_pcs, bufP1, bufC0, Nc);

    norm_kernel<<<(Np + 3) / 4, 256, 0, stream>>>(outP, bufP1, bufP0, Np);
    norm_kernel<<<(Nc + 3) / 4, 256, 0, stream>>>(outC, bufC1, bufC0, Nc);
}

// Round 7
// 688.459 us; speedup vs baseline: 2.2101x; 1.0551x over previous
//
#include <hip/hip_runtime.h>
#include <hip/hip_bf16.h>
#include <math.h>

#define HD 128   // HIDDEN_DIM
#define KD 256   // INPUT_DIM

// ---- bf16 pack/unpack helpers (storage type: ushort) ----
__device__ __forceinline__ unsigned int pack_bf2(float a, float b) {
    __hip_bfloat162 h;
    h.x = __float2bfloat16(a);
    h.y = __float2bfloat16(b);
    return *(unsigned int*)&h;
}
__device__ __forceinline__ float2 unpack_bf2(unsigned int u) {
    __hip_bfloat162 h = *(__hip_bfloat162*)&u;
    return __bfloat1622float2(h);
}

// ---------------- degree count (int), per relation src & dst ----------------
__global__ void deg_kernel(const int* __restrict__ cps, const int* __restrict__ cpd,
                           const int* __restrict__ pcs, const int* __restrict__ pcd,
                           int* c_cps, int* c_pcs, int* c_cpd, int* c_pcd, int E) {
    int e = blockIdx.x * blockDim.x + threadIdx.x;
    if (e >= E) return;
    atomicAdd(c_cps + cps[e], 1);
    atomicAdd(c_pcs + pcs[e], 1);
    atomicAdd(c_cpd + cpd[e], 1);
    atomicAdd(c_pcd + pcd[e], 1);
}

// ---------------- exclusive scan, 3-phase (1024 elems / block) ----------------
__global__ void scanA(int* data, int* bsums, int n) {
    __shared__ int tmp[256];
    const int t = threadIdx.x;
    const int base = blockIdx.x * 1024 + t * 4;
    int v[4], s = 0;
    #pragma unroll
    for (int i = 0; i < 4; ++i) { v[i] = (base + i < n) ? data[base + i] : 0; s += v[i]; }
    tmp[t] = s;
    __syncthreads();
    for (int off = 1; off < 256; off <<= 1) {
        int x = (t >= off) ? tmp[t - off] : 0;
        __syncthreads();
        tmp[t] += x;
        __syncthreads();
    }
    int ex = tmp[t] - s;   // exclusive prefix within block
    #pragma unroll
    for (int i = 0; i < 4; ++i) { if (base + i < n) data[base + i] = ex; ex += v[i]; }
    if (t == 255) bsums[blockIdx.x] = tmp[255];
}

__global__ void scanB(int* bs, int nb) {   // nb <= 256
    __shared__ int tmp[256];
    const int t = threadIdx.x;
    int v = (t < nb) ? bs[t] : 0;
    tmp[t] = v;
    __syncthreads();
    for (int off = 1; off < 256; off <<= 1) {
        int x = (t >= off) ? tmp[t - off] : 0;
        __syncthreads();
        tmp[t] += x;
        __syncthreads();
    }
    if (t < nb) bs[t] = tmp[t] - v;
}

__global__ void scanC(int* data, const int* __restrict__ bsums, int n) {
    const int t = threadIdx.x;
    const int base = blockIdx.x * 1024 + t * 4;
    const int add = bsums[blockIdx.x];
    #pragma unroll
    for (int i = 0; i < 4; ++i) if (base + i < n) data[base + i] += add;
}

// ---------------- int degree -> f32 deg^-1/2, in place ----------------
__global__ void inv_inplace(int* cnt, int n) {
    int i = blockIdx.x * blockDim.x + threadIdx.x;
    if (i >= n) return;
    int d = cnt[i];
    float f = (d > 0) ? (1.0f / sqrtf((float)d)) : 0.0f;
    ((float*)cnt)[i] = f;
}

// ---------------- XCD-filtered counting-sort scatter ----------------
// 8 dst-range groups; group g = blockIdx.x & 7 (round-robin dispatch keeps a
// group's blocks on one XCD). Each group streams ALL edges (cheap: L3-shared)
// but scatters only dst in its 1/8 range -> its write frontier is a ~500 KB
// contiguous CSR region, XCD-local in L2 -> full-line writebacks instead of
// 16x-amplified partial lines. Correct under ANY blockIdx->XCD mapping.
__global__ void scatter_filtered(const int* __restrict__ src, const int* __restrict__ dst,
                                 int* __restrict__ cur, int* __restrict__ out,
                                 int E, int M) {
    const int g  = blockIdx.x & 7;
    const int ib = blockIdx.x >> 3;
    const int nb = gridDim.x >> 3;
    const int lo = (int)(((long)M * g) >> 3);
    const int hi = (int)(((long)M * (g + 1)) >> 3);
    const int stride = nb * 256;
    for (int e = ib * 256 + threadIdx.x; e < E; e += stride) {
        const int d = dst[e];
        const int s = src[e];
        if (d >= lo && d < hi) {
            int p = atomicAdd(cur + d, 1);
            out[p] = s;
        }
    }
}

// ---------------- fp32 GEMM: out = X[M,256] @ W[256,128] + b ----------------
// 128x128 tile, 256 threads, 8x8 thread tile, K chunked by 32, both operands
// in LDS (conflict-free: X row pad +1 f4; W consecutive-f4 per 16 lanes).
// Epilogue writes bf16 h-buffer (out0) AND fp32 acc seed (out1 = d_out).
__device__ __forceinline__ void fma4(float4& a, float s, const float4 w) {
    a.x = fmaf(s, w.x, a.x); a.y = fmaf(s, w.y, a.y);
    a.z = fmaf(s, w.z, a.z); a.w = fmaf(s, w.w, a.w);
}

__launch_bounds__(256, 3)
__global__ void gemm_kernel(const float* __restrict__ X, const float* __restrict__ W,
                            const float* __restrict__ bias, unsigned short* __restrict__ out0,
                            float* __restrict__ out1, int M) {
    __shared__ float4 xs[128 * 9];   // 18 KiB (row stride 9 f4: +1 pad)
    __shared__ float4 ws[32 * 32];   // 16 KiB
    const int t = threadIdx.x;
    const int tcol = t & 15;         // col groups: 4*tcol and 64+4*tcol
    const int trow = t >> 4;         // rows trow + r*16
    const int rbase = blockIdx.x * 128;
    const float4* X4 = (const float4*)X;
    const float4* W4 = (const float4*)W;

    float4 acc[8][2];
    const float4 b0 = ((const float4*)bias)[tcol];
    const float4 b1 = ((const float4*)bias)[16 + tcol];
    #pragma unroll
    for (int r = 0; r < 8; ++r) { acc[r][0] = b0; acc[r][1] = b1; }

    for (int kc = 0; kc < 8; ++kc) {           // 8 chunks of BK=32
        __syncthreads();
        #pragma unroll
        for (int i = 0; i < 4; ++i) {          // stage X: 1024 f4
            int q = t + i * 256;
            int row = q >> 3, c = q & 7;
            int g = rbase + row;
            xs[row * 9 + c] = (g < M) ? X4[(size_t)g * 64 + kc * 8 + c]
                                      : make_float4(0.f, 0.f, 0.f, 0.f);
        }
        #pragma unroll
        for (int i = 0; i < 4; ++i) {          // stage W: 1024 f4
            int q = t + i * 256;
            int krow = q >> 5, c = q & 31;
            ws[q] = W4[(size_t)(kc * 32 + krow) * 32 + c];
        }
        __syncthreads();

        #pragma unroll 2
        for (int kk = 0; kk < 8; ++kk) {       // k4 steps within chunk
            float4 xr[8];
            #pragma unroll
            for (int r = 0; r < 8; ++r) xr[r] = xs[(trow + r * 16) * 9 + kk];
            #pragma unroll
            for (int i = 0; i < 4; ++i) {
                const float4 wa = ws[(kk * 4 + i) * 32 + tcol];
                const float4 wb = ws[(kk * 4 + i) * 32 + 16 + tcol];
                #pragma unroll
                for (int r = 0; r < 8; ++r) {
                    float s = (i == 0) ? xr[r].x : (i == 1) ? xr[r].y
                            : (i == 2) ? xr[r].z : xr[r].w;
                    fma4(acc[r][0], s, wa);
                    fma4(acc[r][1], s, wb);
                }
            }
        }
    }

    #pragma unroll
    for (int r = 0; r < 8; ++r) {
        int g = rbase + trow + r * 16;
        if (g < M) {
            // fp32 acc seed
            ((float4*)out1)[(size_t)g * 32 + tcol]      = acc[r][0];
            ((float4*)out1)[(size_t)g * 32 + 16 + tcol] = acc[r][1];
            // bf16 h-buffer
            uint2 ua, ub;
            ua.x = pack_bf2(acc[r][0].x, acc[r][0].y);
            ua.y = pack_bf2(acc[r][0].z, acc[r][0].w);
            ub.x = pack_bf2(acc[r][1].x, acc[r][1].y);
            ub.y = pack_bf2(acc[r][1].z, acc[r][1].w);
            uint2* o = (uint2*)(out0 + (size_t)g * HD);
            o[tcol]      = ua;
            o[16 + tcol] = ub;
        }
    }
}

// ---------------- CSR aggregation: one 64-lane wave per dst row ----------------
// bf16 h-rows: 256 B/row, gathered by 16 lanes x 16 B. Four 16-lane quarters
// process edges jj..jj+3 concurrently. Shuffles UNCONDITIONAL under full exec
// (round-3 lesson). Offsets: off[row] = END, off[row-1] = start; off[-1] is a
// guaranteed valid word (0 for the cp table, E for the pc table, by layout).
__global__ void agg_csr(const int* __restrict__ off, const int* __restrict__ ssrc,
                        const float* __restrict__ invs,
                        const unsigned short* __restrict__ hsrc,
                        unsigned short* __restrict__ hdst, int M) {
    int row = blockIdx.x * 4 + (threadIdx.x >> 6);
    if (row >= M) return;
    const int lane = threadIdx.x & 63;
    const int q  = lane >> 4;    // edge slot 0..3
    const int cl = lane & 15;    // column group: floats cl*8 .. +7
    const int end = off[row];
    const int beg = off[row - 1];
    float4 accA = make_float4(0.f, 0.f, 0.f, 0.f);
    float4 accB = make_float4(0.f, 0.f, 0.f, 0.f);
    const int deg = end - beg;
    if (deg > 0) {
        const float id = 1.0f / sqrtf((float)deg);
        for (int base = beg; base < end; base += 64) {
            int n = end - base;
            if (n > 64) n = 64;
            int sl = 0; float wl = 0.f;
            if (lane < n) {
                sl = ssrc[base + lane];
                wl = invs[sl];
            }
            for (int jj = 0; jj < n; jj += 4) {
                const int j = jj + q;                 // <= 63 always
                const int s = __shfl(sl, j);
                const float wt = __shfl(wl, j) * id;  // 0 when j >= n
                const uint4 u = *(const uint4*)(hsrc + (size_t)s * HD + cl * 8);
                const float2 f0 = unpack_bf2(u.x);
                const float2 f1 = unpack_bf2(u.y);
                const float2 f2 = unpack_bf2(u.z);
                const float2 f3 = unpack_bf2(u.w);
                accA.x = fmaf(f0.x, wt, accA.x);
                accA.y = fmaf(f0.y, wt, accA.y);
                accA.z = fmaf(f1.x, wt, accA.z);
                accA.w = fmaf(f1.y, wt, accA.w);
                accB.x = fmaf(f2.x, wt, accB.x);
                accB.y = fmaf(f2.y, wt, accB.y);
                accB.z = fmaf(f3.x, wt, accB.z);
                accB.w = fmaf(f3.y, wt, accB.w);
            }
        }
    }
    // combine the 4 quarters: lanes {cl, cl+16, cl+32, cl+48} share columns
    accA.x += __shfl_xor(accA.x, 16); accA.y += __shfl_xor(accA.y, 16);
    accA.z += __shfl_xor(accA.z, 16); accA.w += __shfl_xor(accA.w, 16);
    accB.x += __shfl_xor(accB.x, 16); accB.y += __shfl_xor(accB.y, 16);
    accB.z += __shfl_xor(accB.z, 16); accB.w += __shfl_xor(accB.w, 16);
    accA.x += __shfl_xor(accA.x, 32); accA.y += __shfl_xor(accA.y, 32);
    accA.z += __shfl_xor(accA.z, 32); accA.w += __shfl_xor(accA.w, 32);
    accB.x += __shfl_xor(accB.x, 32); accB.y += __shfl_xor(accB.y, 32);
    accB.z += __shfl_xor(accB.z, 32); accB.w += __shfl_xor(accB.w, 32);
    if (q == 0) {
        uint4 u;
        u.x = pack_bf2(accA.x, accA.y);
        u.y = pack_bf2(accA.z, accA.w);
        u.z = pack_bf2(accB.x, accB.y);
        u.w = pack_bf2(accB.z, accB.w);
        *(uint4*)(hdst + (size_t)row * HD + cl * 8) = u;
    }
}

// ---------------- final: acc = (h0 + l1 + l2)/3, L2-normalize rows ----------------
__global__ void norm_kernel(float* __restrict__ accOut,
                            const unsigned short* __restrict__ b1,
                            const unsigned short* __restrict__ b2, int M) {
    int row = blockIdx.x * 4 + (threadIdx.x >> 6);
    if (row >= M) return;
    int lane = threadIdx.x & 63;
    size_t base = (size_t)row * HD + (size_t)lane * 2;
    float2 a  = *(const float2*)(accOut + base);
    float2 x1 = unpack_bf2(*(const unsigned int*)(b1 + base));
    float2 x2 = unpack_bf2(*(const unsigned int*)(b2 + base));
    const float s = 1.0f / 3.0f;
    float vx = (a.x + x1.x + x2.x) * s;
    float vy = (a.y + x1.y + x2.y) * s;
    float ss = vx * vx + vy * vy;
    #pragma unroll
    for (int off = 32; off > 0; off >>= 1) ss += __shfl_xor(ss, off);
    float inv = 1.0f / fmaxf(sqrtf(ss), 1e-12f);
    float2 r = make_float2(vx * inv, vy * inv);
    *(float2*)(accOut + base) = r;
}

extern "C" void kernel_launch(void* const* d_in, const int* in_sizes, int n_in,
                              void* d_out, int out_size, void* d_ws, size_t ws_size,
                              hipStream_t stream) {
    const float* x_p = (const float*)d_in[0];
    const float* x_c = (const float*)d_in[1];
    const float* W_p = (const float*)d_in[2];
    const float* b_p = (const float*)d_in[3];
    const float* W_c = (const float*)d_in[4];
    const float* b_c = (const float*)d_in[5];
    const int* pcs = (const int*)d_in[6];
    const int* pcd = (const int*)d_in[7];
    const int* cps = (const int*)d_in[8];
    const int* cpd = (const int*)d_in[9];

    const int Np = in_sizes[0] / KD;
    const int Nc = in_sizes[1] / KD;
    const int E  = in_sizes[6];

    // ---- workspace layout (4B words) ----
    // scp: COMBINED dst-sorted src array [2E]: cp lists at [0,E), pc at [E,2E)
    // cnt: [c_cps Nc][c_pcs Np][zeroword][c_cpd Np][c_pcd Nc]
    //   single scan over (c_cpd|c_pcd) pre-offsets pc cursors by +E; the zero
    //   word makes off[-1] valid for cp (0); for pc, off[-1]=c_cpd[Np-1]=E.
    int* scp = (int*)d_ws;                             // [2E]
    int* cnt = scp + 2 * (size_t)E;
    int* c_cps = cnt;                                  // [Nc] -> f32 inv
    int* c_pcs = c_cps + Nc;                           // [Np] -> f32 inv
    int* zw    = c_pcs + Np;                           // [1]  stays 0
    int* c_cpd = zw + 1;                               // [Np] -> off_cp
    int* c_pcd = c_cpd + Np;                           // [Nc] -> off_pc
    unsigned short* bufP0 = (unsigned short*)(c_pcd + Nc);   // [Np*HD] bf16
    unsigned short* bufP1 = bufP0 + (size_t)Np * HD;
    unsigned short* bufC0 = bufP1 + (size_t)Np * HD;
    unsigned short* bufC1 = bufC0 + (size_t)Nc * HD;

    float* outP = (float*)d_out;
    float* outC = outP + (size_t)Np * HD;

    int* bsumA = (int*)d_out;        // scan block sums, overwritten by GEMM later

    const int ncnt = 2 * (Np + Nc) + 1;
    const int nscan = Np + Nc;
    const int nblk = (nscan + 1023) / 1024;

    hipMemsetAsync(cnt, 0, (size_t)ncnt * sizeof(int), stream);

    deg_kernel<<<(E + 255) / 256, 256, 0, stream>>>(cps, cpd, pcs, pcd,
                                                    c_cps, c_pcs, c_cpd, c_pcd, E);
    // single combined exclusive scan over [c_cpd | c_pcd]
    scanA<<<nblk, 256, 0, stream>>>(c_cpd, bsumA, nscan);
    scanB<<<1, 256, 0, stream>>>(bsumA, nblk);
    scanC<<<nblk, 256, 0, stream>>>(c_cpd, bsumA, nscan);

    inv_inplace<<<(Nc + Np + 255) / 256, 256, 0, stream>>>(cnt, Nc + Np);

    // XCD-filtered scatters (cursors advance to END offsets)
    scatter_filtered<<<832, 256, 0, stream>>>(cps, cpd, c_cpd, scp, E, Np);
    scatter_filtered<<<832, 256, 0, stream>>>(pcs, pcd, c_pcd, scp, E, Nc);

    gemm_kernel<<<(Np + 127) / 128, 256, 0, stream>>>(x_p, W_p, b_p, bufP0, outP, Np);
    gemm_kernel<<<(Nc + 127) / 128, 256, 0, stream>>>(x_c, W_c, b_c, bufC0, outC, Nc);

    const float* i_cps = (const float*)c_cps;
    const float* i_pcs = (const float*)c_pcs;

    // layer 1
    agg_csr<<<(Np + 3) / 4, 256, 0, stream>>>(c_cpd, scp, i_cps, bufC0, bufP1, Np);
    agg_csr<<<(Nc + 3) / 4, 256, 0, stream>>>(c_pcd, scp, i_pcs, bufP0, bufC1, Nc);
    // layer 2 (overwrites consumed layer-0 buffers; agg writes every row)
    agg_csr<<<(Np + 3) / 4, 256, 0, stream>>>(c_cpd, scp, i_cps, bufC1, bufP0, Np);
    agg_csr<<<(Nc + 3) / 4, 256, 0, stream>>>(c_pcd, scp, i_pcs, bufP1, bufC0, Nc);

    norm_kernel<<<(Np + 3) / 4, 256, 0, stream>>>(outP, bufP1, bufP0, Np);
    norm_kernel<<<(Nc + 3) / 4, 256, 0, stream>>>(outC, bufC1, bufC0, Nc);
}